// Round 2
// baseline (183.604 us; speedup 1.0000x reference)
//
#include <hip/hip_runtime.h>

// ---------------------------------------------------------------------------
// MultiHeadSelfAttentionWithRoPE  (B=2, S=2048, D=1024, H=16, d=64, causal)
// Pipeline: cvt(fp32->bf16) -> QKV gemm (MFMA bf16) -> RoPE -> flash attn
//           (MFMA bf16, online softmax) -> O gemm (MFMA bf16, fp32 out)
// ---------------------------------------------------------------------------

typedef unsigned short u16;
typedef unsigned int   u32;
typedef u16    ushort8 __attribute__((ext_vector_type(8)));
typedef __bf16 bf16x8  __attribute__((ext_vector_type(8)));
typedef float  f32x4   __attribute__((ext_vector_type(4)));

#define D_MODEL 1024
#define SEQ     2048
#define NHEAD   16
#define HDIM    64
#define NTOK    4096   // B*S
#define SEG     1048576

__device__ __forceinline__ u16 f2bf(float f) {        // RNE fp32->bf16
    u32 u = __builtin_bit_cast(u32, f);
    u32 r = (u + 0x7FFFu + ((u >> 16) & 1u)) >> 16;
    return (u16)r;
}
__device__ __forceinline__ float bf2f(u16 h) {
    return __builtin_bit_cast(float, (u32)h << 16);
}
__device__ __forceinline__ bf16x8 as_bf(ushort8 v) {
    return __builtin_bit_cast(bf16x8, v);
}
__device__ __forceinline__ f32x4 mfma16(bf16x8 a, bf16x8 b, f32x4 c) {
    return __builtin_amdgcn_mfma_f32_16x16x32_bf16(a, b, c, 0, 0, 0);
}

// ---------------------------------------------------------------------------
// fp32 -> bf16 conversion: z<4 quarters of x, z=4..7 -> W_Q,W_K,W_V,W_O
// ---------------------------------------------------------------------------
__global__ __launch_bounds__(256) void k_cvt(
    const float* __restrict__ x,  const float* __restrict__ wq,
    const float* __restrict__ wk, const float* __restrict__ wv,
    const float* __restrict__ wo, u16* __restrict__ dst0)
{
    const int z = blockIdx.z;
    const float* src; u16* dst;
    if      (z < 4)  { src = x + (size_t)z * SEG; dst = dst0 + (size_t)z * SEG; }
    else if (z == 4) { src = wq; dst = dst0 + (size_t)4 * SEG; }
    else if (z == 5) { src = wk; dst = dst0 + (size_t)5 * SEG; }
    else if (z == 6) { src = wv; dst = dst0 + (size_t)6 * SEG; }
    else             { src = wo; dst = dst0 + (size_t)7 * SEG; }
    const size_t i = ((size_t)blockIdx.x * 256 + threadIdx.x) * 8;
    f32x4 f0 = *(const f32x4*)(src + i);
    f32x4 f1 = *(const f32x4*)(src + i + 4);
    ushort8 o;
    o[0]=f2bf(f0[0]); o[1]=f2bf(f0[1]); o[2]=f2bf(f0[2]); o[3]=f2bf(f0[3]);
    o[4]=f2bf(f1[0]); o[5]=f2bf(f1[1]); o[6]=f2bf(f1[2]); o[7]=f2bf(f1[3]);
    *(ushort8*)(dst + i) = o;
}

// ---------------------------------------------------------------------------
// NT GEMM core: C[M,N] = A[M,K] * W[N,K]^T, K=1024, 128x128 block tile,
// 4 waves (2x2), each 64x64 via 4x4 mfma_16x16x32 fragments, BK=32,
// reg-staged double-buffered LDS with (row&3)<<4 XOR swizzle.
// ---------------------------------------------------------------------------
template<bool BHSD>
__device__ __forceinline__ void gemm_body(
    const u16* __restrict__ A, const u16* __restrict__ W,
    u16* __restrict__ outB, float* __restrict__ outF, int bm, int bn)
{
    __shared__ u16 Als[2][128 * 32];
    __shared__ u16 Bls[2][128 * 32];
    const int tid  = threadIdx.x;
    const int lane = tid & 63;
    const int wv   = tid >> 6;
    const int wm   = wv >> 1, wn = wv & 1;
    const int l15  = lane & 15, l4 = lane >> 4;

    // staging: 512 chunks of 16B per tile-buffer, 2 per thread
    const int c0 = tid, c1 = tid + 256;
    const int r0 = c0 >> 2, p0 = c0 & 3;
    const int r1 = c1 >> 2, p1 = c1 & 3;
    const u16* gA0 = A + (size_t)(bm + r0) * D_MODEL + p0 * 8;
    const u16* gA1 = A + (size_t)(bm + r1) * D_MODEL + p1 * 8;
    const u16* gB0 = W + (size_t)(bn + r0) * D_MODEL + p0 * 8;
    const u16* gB1 = W + (size_t)(bn + r1) * D_MODEL + p1 * 8;
    const int lo0 = r0 * 64 + ((p0 * 16) ^ ((r0 & 3) << 4));
    const int lo1 = r1 * 64 + ((p1 * 16) ^ ((r1 & 3) << 4));

    const f32x4 zz = {0.f, 0.f, 0.f, 0.f};
    f32x4 acc[4][4];
#pragma unroll
    for (int i = 0; i < 4; i++)
#pragma unroll
        for (int j = 0; j < 4; j++) acc[i][j] = zz;

    ushort8 sa0 = *(const ushort8*)gA0;
    ushort8 sa1 = *(const ushort8*)gA1;
    ushort8 sb0 = *(const ushort8*)gB0;
    ushort8 sb1 = *(const ushort8*)gB1;
    *(ushort8*)((char*)&Als[0][0] + lo0) = sa0;
    *(ushort8*)((char*)&Als[0][0] + lo1) = sa1;
    *(ushort8*)((char*)&Bls[0][0] + lo0) = sb0;
    *(ushort8*)((char*)&Bls[0][0] + lo1) = sb1;
    __syncthreads();

    for (int t = 0; t < 32; ++t) {
        const int cur = t & 1;
        if (t < 31) {
            const int k0 = (t + 1) * 32;
            sa0 = *(const ushort8*)(gA0 + k0);
            sa1 = *(const ushort8*)(gA1 + k0);
            sb0 = *(const ushort8*)(gB0 + k0);
            sb1 = *(const ushort8*)(gB1 + k0);
        }
        bf16x8 af[4], bfr[4];
#pragma unroll
        for (int mi = 0; mi < 4; mi++) {
            const int row = wm * 64 + mi * 16 + l15;
            af[mi] = as_bf(*(const ushort8*)((const char*)&Als[cur][0] +
                         row * 64 + ((l4 * 16) ^ ((row & 3) << 4))));
        }
#pragma unroll
        for (int ni = 0; ni < 4; ni++) {
            const int row = wn * 64 + ni * 16 + l15;
            bfr[ni] = as_bf(*(const ushort8*)((const char*)&Bls[cur][0] +
                          row * 64 + ((l4 * 16) ^ ((row & 3) << 4))));
        }
#pragma unroll
        for (int mi = 0; mi < 4; mi++)
#pragma unroll
            for (int ni = 0; ni < 4; ni++)
                acc[mi][ni] = mfma16(af[mi], bfr[ni], acc[mi][ni]);
        __syncthreads();
        if (t < 31) {
            const int nxt = cur ^ 1;
            *(ushort8*)((char*)&Als[nxt][0] + lo0) = sa0;
            *(ushort8*)((char*)&Als[nxt][0] + lo1) = sa1;
            *(ushort8*)((char*)&Bls[nxt][0] + lo0) = sb0;
            *(ushort8*)((char*)&Bls[nxt][0] + lo1) = sb1;
            __syncthreads();
        }
    }

#pragma unroll
    for (int mi = 0; mi < 4; mi++)
#pragma unroll
        for (int ni = 0; ni < 4; ni++) {
            const int rowb = bm + wm * 64 + mi * 16 + l4 * 4;
            const int colg = bn + wn * 64 + ni * 16 + l15;
#pragma unroll
            for (int r = 0; r < 4; r++) {
                const float v = acc[mi][ni][r];
                const int rowg = rowb + r;
                if constexpr (BHSD) {
                    const int b = rowg >> 11, s = rowg & 2047;
                    const int h = colg >> 6,  d = colg & 63;
                    outB[((size_t)(b * NHEAD + h) * SEQ + s) * HDIM + d] = f2bf(v);
                } else {
                    outF[(size_t)rowg * D_MODEL + colg] = v;
                }
            }
        }
}

__global__ __launch_bounds__(256) void k_gemm_qkv(
    const u16* __restrict__ xb,
    const u16* __restrict__ wq, const u16* __restrict__ wk, const u16* __restrict__ wv,
    u16* __restrict__ Qb, u16* __restrict__ Kb, u16* __restrict__ Vb)
{
    const int z = blockIdx.z;
    const u16* W = (z == 0) ? wq : (z == 1) ? wk : wv;
    u16*       O = (z == 0) ? Qb : (z == 1) ? Kb : Vb;
    gemm_body<true>(xb, W, O, nullptr, blockIdx.y * 128, blockIdx.x * 128);
}

__global__ __launch_bounds__(256) void k_gemm_o(
    const u16* __restrict__ yb, const u16* __restrict__ wo, float* __restrict__ out)
{
    gemm_body<false>(yb, wo, nullptr, out, blockIdx.y * 128, blockIdx.x * 128);
}

// ---------------------------------------------------------------------------
// RoPE in place on Q (z=0, also folds 1/sqrt(d)=0.125) and K (z=1).
// pair p of head dim: out[2p]   = x[2p]*cos - x[2p+1]*sin
//                     out[2p+1] = x[2p]*sin + x[2p+1]*cos
// angle = pos * theta^(-p/32),  theta=1e4 -> exp2(-p*log2(1e4)/32)
// ---------------------------------------------------------------------------
__global__ __launch_bounds__(256) void k_rope(
    u16* __restrict__ Qb, u16* __restrict__ Kb, const int* __restrict__ pos)
{
    const int z = blockIdx.y;
    u32* T = (u32*)(z ? Kb : Qb);
    const float scale = z ? 1.0f : 0.125f;
    const int idx = blockIdx.x * 256 + threadIdx.x;    // (bh*2048+s)*32+p
    const int p = idx & 31;
    const int s = (idx >> 5) & 2047;
    const float ps  = (float)pos[s];
    const float ang = ps * exp2f(-(float)p * 0.41524101186092435f);
    float sn, cs;
    sincosf(ang, &sn, &cs);
    const u32 v = T[idx];
    const float x0 = bf2f((u16)(v & 0xffffu));
    const float x1 = bf2f((u16)(v >> 16));
    const float r0a = (x0 * cs - x1 * sn) * scale;
    const float r1a = (x0 * sn + x1 * cs) * scale;
    T[idx] = (u32)f2bf(r0a) | ((u32)f2bf(r1a) << 16);
}

// ---------------------------------------------------------------------------
// Causal flash attention. Block = 4 waves x 32 queries = 128 q per (b,h).
// K tile [64 keys][64 dims] in LDS (swizzled); V staged transposed
// Vt[dim][key] (swizzled) so PV B-frags are contiguous b128 reads.
// Online softmax per query row via 16-lane shfl_xor reductions.
// ---------------------------------------------------------------------------
__global__ __launch_bounds__(256) void k_attn(
    const u16* __restrict__ Qb, const u16* __restrict__ Kb,
    const u16* __restrict__ Vb, u16* __restrict__ Yb)
{
    __shared__ u16 Kls[64 * 64];
    __shared__ u16 Vtls[64 * 64];
    __shared__ u16 Pls[4][32 * 64];
    const int tid  = threadIdx.x;
    const int lane = tid & 63, wv = tid >> 6;
    const int l15  = lane & 15, l4 = lane >> 4;
    const int bh    = blockIdx.x;           // b*16+h
    const int qbase = blockIdx.y * 128;
    const int qw    = qbase + wv * 32;      // wave's first query
    const size_t base = (size_t)bh * SEQ * HDIM;
    const u16* Qg = Qb + base;
    const u16* Kg = Kb + base;
    const u16* Vg = Vb + base;

    // Q fragments (scale already folded in by k_rope)
    bf16x8 qf[2][2];
#pragma unroll
    for (int mt = 0; mt < 2; mt++)
#pragma unroll
        for (int ks = 0; ks < 2; ks++)
            qf[mt][ks] = as_bf(*(const ushort8*)(
                Qg + (size_t)(qw + mt * 16 + l15) * HDIM + ks * 32 + l4 * 8));

    const f32x4 zz = {0.f, 0.f, 0.f, 0.f};
    f32x4 acc[2][4];
    float mst[2][4], lst[2][4];
#pragma unroll
    for (int mt = 0; mt < 2; mt++) {
#pragma unroll
        for (int n = 0; n < 4; n++) acc[mt][n] = zz;
#pragma unroll
        for (int r = 0; r < 4; r++) { mst[mt][r] = -1e30f; lst[mt][r] = 0.f; }
    }

    const int cA = tid, cB = tid + 256;
    const int kr0 = cA >> 3, kp0 = cA & 7, kr1 = cB >> 3, kp1 = cB & 7;
    const int vk0 = cA & 63, vd0 = cA >> 6, vk1 = cB & 63, vd1 = cB >> 6;

    const int nkb = qbase / 64 + 2;
    for (int kb = 0; kb < nkb; ++kb) {
        const int kbb = kb * 64;
        // --- stage K (row-major, swizzled) and V (transposed, swizzled) ---
        ushort8 tk0 = *(const ushort8*)(Kg + (size_t)(kbb + kr0) * HDIM + kp0 * 8);
        ushort8 tk1 = *(const ushort8*)(Kg + (size_t)(kbb + kr1) * HDIM + kp1 * 8);
        ushort8 tv0 = *(const ushort8*)(Vg + (size_t)(kbb + vk0) * HDIM + vd0 * 8);
        ushort8 tv1 = *(const ushort8*)(Vg + (size_t)(kbb + vk1) * HDIM + vd1 * 8);
        *(ushort8*)((char*)Kls + kr0 * 128 + ((kp0 * 16) ^ ((kr0 & 7) << 4))) = tk0;
        *(ushort8*)((char*)Kls + kr1 * 128 + ((kp1 * 16) ^ ((kr1 & 7) << 4))) = tk1;
#pragma unroll
        for (int j = 0; j < 8; j++) {
            const int d0 = vd0 * 8 + j, d1 = vd1 * 8 + j;
            *((u16*)((char*)Vtls + d0 * 128 + ((vk0 * 2) ^ ((d0 & 7) << 4)))) = tv0[j];
            *((u16*)((char*)Vtls + d1 * 128 + ((vk1 * 2) ^ ((d1 & 7) << 4)))) = tv1[j];
        }
        __syncthreads();

        if (kbb <= qw + 31) {   // wave-uniform: any of this wave's queries live?
            // --- S = Q K^T ---
            bf16x8 kf[4][2];
#pragma unroll
            for (int nt = 0; nt < 4; nt++)
#pragma unroll
                for (int ks = 0; ks < 2; ks++) {
                    const int row = nt * 16 + l15;
                    kf[nt][ks] = as_bf(*(const ushort8*)((const char*)Kls +
                        row * 128 + ((ks * 64 + l4 * 16) ^ ((row & 7) << 4))));
                }
            f32x4 sfr[2][4];
#pragma unroll
            for (int mt = 0; mt < 2; mt++)
#pragma unroll
                for (int nt = 0; nt < 4; nt++) {
                    f32x4 sv = zz;
                    sv = mfma16(qf[mt][0], kf[nt][0], sv);
                    sv = mfma16(qf[mt][1], kf[nt][1], sv);
                    sfr[mt][nt] = sv;
                }

            // --- mask + online softmax ---
#pragma unroll
            for (int mt = 0; mt < 2; mt++) {
                const int q0 = qw + mt * 16 + l4 * 4;  // + r
#pragma unroll
                for (int nt = 0; nt < 4; nt++) {
                    const int key = kbb + nt * 16 + l15;
#pragma unroll
                    for (int r = 0; r < 4; r++)
                        sfr[mt][nt][r] = (key <= q0 + r) ? sfr[mt][nt][r] : -1e30f;
                }
                float rmax[4];
#pragma unroll
                for (int r = 0; r < 4; r++) {
                    float m = fmaxf(fmaxf(sfr[mt][0][r], sfr[mt][1][r]),
                                    fmaxf(sfr[mt][2][r], sfr[mt][3][r]));
#pragma unroll
                    for (int off = 1; off < 16; off <<= 1)
                        m = fmaxf(m, __shfl_xor(m, off));
                    rmax[r] = m;
                }
                float sf[4];
#pragma unroll
                for (int r = 0; r < 4; r++) {
                    const float mnew = fmaxf(mst[mt][r], rmax[r]);
                    sf[r] = __expf(mst[mt][r] - mnew);
                    mst[mt][r] = mnew;
                }
                float psum[4] = {0.f, 0.f, 0.f, 0.f};
#pragma unroll
                for (int nt = 0; nt < 4; nt++) {
#pragma unroll
                    for (int r = 0; r < 4; r++) {
                        const float pv = __expf(sfr[mt][nt][r] - mst[mt][r]);
                        psum[r] += pv;
                        const int prow = mt * 16 + l4 * 4 + r;
                        const int pcol = nt * 16 + l15;
                        *((u16*)((char*)&Pls[wv][0] + prow * 128 +
                                 ((pcol * 2) ^ ((prow & 7) << 4)))) = f2bf(pv);
                    }
                }
#pragma unroll
                for (int r = 0; r < 4; r++) {
                    float s = psum[r];
#pragma unroll
                    for (int off = 1; off < 16; off <<= 1) s += __shfl_xor(s, off);
                    lst[mt][r] = lst[mt][r] * sf[r] + s;
                }
#pragma unroll
                for (int nd = 0; nd < 4; nd++)
#pragma unroll
                    for (int r = 0; r < 4; r++) acc[mt][nd][r] *= sf[r];
            }

            // --- O += P V ---
            bf16x8 vf[4][2];
#pragma unroll
            for (int nd = 0; nd < 4; nd++)
#pragma unroll
                for (int ks = 0; ks < 2; ks++) {
                    const int row = nd * 16 + l15;
                    vf[nd][ks] = as_bf(*(const ushort8*)((const char*)Vtls +
                        row * 128 + ((ks * 64 + l4 * 16) ^ ((row & 7) << 4))));
                }
#pragma unroll
            for (int mt = 0; mt < 2; mt++) {
                bf16x8 pf[2];
#pragma unroll
                for (int ks = 0; ks < 2; ks++) {
                    const int row = mt * 16 + l15;
                    pf[ks] = as_bf(*(const ushort8*)((const char*)&Pls[wv][0] +
                        row * 128 + ((ks * 64 + l4 * 16) ^ ((row & 7) << 4))));
                }
#pragma unroll
                for (int nd = 0; nd < 4; nd++) {
                    acc[mt][nd] = mfma16(pf[0], vf[nd][0], acc[mt][nd]);
                    acc[mt][nd] = mfma16(pf[1], vf[nd][1], acc[mt][nd]);
                }
            }
        }
        __syncthreads();
    }

    // --- epilogue: y[token][h*64+d] = acc / l ---
    const int b = bh >> 4, h = bh & 15;
#pragma unroll
    for (int mt = 0; mt < 2; mt++)
#pragma unroll
        for (int nd = 0; nd < 4; nd++)
#pragma unroll
            for (int r = 0; r < 4; r++) {
                const int q = qw + mt * 16 + l4 * 4 + r;
                const int d = nd * 16 + l15;
                const float v = acc[mt][nd][r] / lst[mt][r];
                Yb[(size_t)(b * SEQ + q) * D_MODEL + h * HDIM + d] = f2bf(v);
            }
}

// ---------------------------------------------------------------------------
extern "C" void kernel_launch(void* const* d_in, const int* in_sizes, int n_in,
                              void* d_out, int out_size, void* d_ws, size_t ws_size,
                              hipStream_t stream)
{
    const float* x  = (const float*)d_in[0];
    const float* wq = (const float*)d_in[1];
    const float* wk = (const float*)d_in[2];
    const float* wv = (const float*)d_in[3];
    const float* wo = (const float*)d_in[4];
    const int*  pos = (const int*)d_in[5];
    float* out = (float*)d_out;

    // workspace layout (bf16 elements):
    // [x 4M | wq 1M | wk 1M | wv 1M | wo 1M | Q 4M | K 4M | V 4M] = 40 MiB
    // y (attention output) aliases x (x is dead after the QKV GEMM).
    if (ws_size < (size_t)41943040) return;
    u16* xb  = (u16*)d_ws;
    u16* wqb = xb  + (size_t)4 * SEG;
    u16* wkb = wqb + SEG;
    u16* wvb = wkb + SEG;
    u16* wob = wvb + SEG;
    u16* Qb  = wob + SEG;
    u16* Kb  = Qb  + (size_t)4 * SEG;
    u16* Vb  = Kb  + (size_t)4 * SEG;
    u16* Yb  = xb;

    k_cvt     <<<dim3(512, 1, 8), 256, 0, stream>>>(x, wq, wk, wv, wo, xb);
    k_gemm_qkv<<<dim3(8, 32, 3),  256, 0, stream>>>(xb, wqb, wkb, wvb, Qb, Kb, Vb);
    k_rope    <<<dim3(8192, 2),   256, 0, stream>>>(Qb, Kb, pos);
    k_attn    <<<dim3(32, 16),    256, 0, stream>>>(Qb, Kb, Vb, Yb);
    k_gemm_o  <<<dim3(8, 32),     256, 0, stream>>>(Yb, wob, out);
}

// Round 3
// 183.374 us; speedup vs baseline: 1.0013x; 1.0013x over previous
//
#include <hip/hip_runtime.h>

// ---------------------------------------------------------------------------
// MultiHeadSelfAttentionWithRoPE  (B=2, S=2048, D=1024, H=16, d=64, causal)
// Pipeline: cvt(fp32->bf16) -> QKV gemm (MFMA bf16) -> RoPE -> flash attn
//           (MFMA bf16, online softmax) -> O gemm (MFMA bf16, fp32 out)
// ---------------------------------------------------------------------------

typedef unsigned short u16;
typedef unsigned int   u32;
typedef u16    ushort8 __attribute__((ext_vector_type(8)));
typedef __bf16 bf16x8  __attribute__((ext_vector_type(8)));
typedef float  f32x4   __attribute__((ext_vector_type(4)));

#define D_MODEL 1024
#define SEQ     2048
#define NHEAD   16
#define HDIM    64
#define NTOK    4096   // B*S
#define SEG     1048576

__device__ __forceinline__ u16 f2bf(float f) {        // RNE fp32->bf16
    u32 u = __builtin_bit_cast(u32, f);
    u32 r = (u + 0x7FFFu + ((u >> 16) & 1u)) >> 16;
    return (u16)r;
}
__device__ __forceinline__ float bf2f(u16 h) {
    return __builtin_bit_cast(float, (u32)h << 16);
}
__device__ __forceinline__ bf16x8 as_bf(ushort8 v) {
    return __builtin_bit_cast(bf16x8, v);
}
__device__ __forceinline__ f32x4 mfma16(bf16x8 a, bf16x8 b, f32x4 c) {
    return __builtin_amdgcn_mfma_f32_16x16x32_bf16(a, b, c, 0, 0, 0);
}

// ---------------------------------------------------------------------------
// fp32 -> bf16 conversion: z<4 quarters of x, z=4..7 -> W_Q,W_K,W_V,W_O
// ---------------------------------------------------------------------------
__global__ __launch_bounds__(256) void k_cvt(
    const float* __restrict__ x,  const float* __restrict__ wq,
    const float* __restrict__ wk, const float* __restrict__ wv,
    const float* __restrict__ wo, u16* __restrict__ dst0)
{
    const int z = blockIdx.z;
    const float* src; u16* dst;
    if      (z < 4)  { src = x + (size_t)z * SEG; dst = dst0 + (size_t)z * SEG; }
    else if (z == 4) { src = wq; dst = dst0 + (size_t)4 * SEG; }
    else if (z == 5) { src = wk; dst = dst0 + (size_t)5 * SEG; }
    else if (z == 6) { src = wv; dst = dst0 + (size_t)6 * SEG; }
    else             { src = wo; dst = dst0 + (size_t)7 * SEG; }
    const size_t i = ((size_t)blockIdx.x * 256 + threadIdx.x) * 8;
    f32x4 f0 = *(const f32x4*)(src + i);
    f32x4 f1 = *(const f32x4*)(src + i + 4);
    ushort8 o;
    o[0]=f2bf(f0[0]); o[1]=f2bf(f0[1]); o[2]=f2bf(f0[2]); o[3]=f2bf(f0[3]);
    o[4]=f2bf(f1[0]); o[5]=f2bf(f1[1]); o[6]=f2bf(f1[2]); o[7]=f2bf(f1[3]);
    *(ushort8*)(dst + i) = o;
}

// ---------------------------------------------------------------------------
// NT GEMM core: C[M,N] = A[M,K] * W[N,K]^T, K=1024, 128x128 block tile,
// 4 waves (2x2), each 64x64 via 4x4 mfma_16x16x32 fragments, BK=32,
// reg-staged double-buffered LDS with (row&3)<<4 XOR swizzle.
// ---------------------------------------------------------------------------
template<bool BHSD>
__device__ __forceinline__ void gemm_body(
    const u16* __restrict__ A, const u16* __restrict__ W,
    u16* __restrict__ outB, float* __restrict__ outF, int bm, int bn)
{
    __shared__ u16 Als[2][128 * 32];
    __shared__ u16 Bls[2][128 * 32];
    const int tid  = threadIdx.x;
    const int lane = tid & 63;
    const int wv   = tid >> 6;
    const int wm   = wv >> 1, wn = wv & 1;
    const int l15  = lane & 15, l4 = lane >> 4;

    // staging: 512 chunks of 16B per tile-buffer, 2 per thread
    const int c0 = tid, c1 = tid + 256;
    const int r0 = c0 >> 2, p0 = c0 & 3;
    const int r1 = c1 >> 2, p1 = c1 & 3;
    const u16* gA0 = A + (size_t)(bm + r0) * D_MODEL + p0 * 8;
    const u16* gA1 = A + (size_t)(bm + r1) * D_MODEL + p1 * 8;
    const u16* gB0 = W + (size_t)(bn + r0) * D_MODEL + p0 * 8;
    const u16* gB1 = W + (size_t)(bn + r1) * D_MODEL + p1 * 8;
    const int lo0 = r0 * 64 + ((p0 * 16) ^ ((r0 & 3) << 4));
    const int lo1 = r1 * 64 + ((p1 * 16) ^ ((r1 & 3) << 4));

    const f32x4 zz = {0.f, 0.f, 0.f, 0.f};
    f32x4 acc[4][4];
#pragma unroll
    for (int i = 0; i < 4; i++)
#pragma unroll
        for (int j = 0; j < 4; j++) acc[i][j] = zz;

    ushort8 sa0 = *(const ushort8*)gA0;
    ushort8 sa1 = *(const ushort8*)gA1;
    ushort8 sb0 = *(const ushort8*)gB0;
    ushort8 sb1 = *(const ushort8*)gB1;
    *(ushort8*)((char*)&Als[0][0] + lo0) = sa0;
    *(ushort8*)((char*)&Als[0][0] + lo1) = sa1;
    *(ushort8*)((char*)&Bls[0][0] + lo0) = sb0;
    *(ushort8*)((char*)&Bls[0][0] + lo1) = sb1;
    __syncthreads();

    for (int t = 0; t < 32; ++t) {
        const int cur = t & 1;
        if (t < 31) {
            const int k0 = (t + 1) * 32;
            sa0 = *(const ushort8*)(gA0 + k0);
            sa1 = *(const ushort8*)(gA1 + k0);
            sb0 = *(const ushort8*)(gB0 + k0);
            sb1 = *(const ushort8*)(gB1 + k0);
        }
        bf16x8 af[4], bfr[4];
#pragma unroll
        for (int mi = 0; mi < 4; mi++) {
            const int row = wm * 64 + mi * 16 + l15;
            af[mi] = as_bf(*(const ushort8*)((const char*)&Als[cur][0] +
                         row * 64 + ((l4 * 16) ^ ((row & 3) << 4))));
        }
#pragma unroll
        for (int ni = 0; ni < 4; ni++) {
            const int row = wn * 64 + ni * 16 + l15;
            bfr[ni] = as_bf(*(const ushort8*)((const char*)&Bls[cur][0] +
                          row * 64 + ((l4 * 16) ^ ((row & 3) << 4))));
        }
#pragma unroll
        for (int mi = 0; mi < 4; mi++)
#pragma unroll
            for (int ni = 0; ni < 4; ni++)
                acc[mi][ni] = mfma16(af[mi], bfr[ni], acc[mi][ni]);
        __syncthreads();
        if (t < 31) {
            const int nxt = cur ^ 1;
            *(ushort8*)((char*)&Als[nxt][0] + lo0) = sa0;
            *(ushort8*)((char*)&Als[nxt][0] + lo1) = sa1;
            *(ushort8*)((char*)&Bls[nxt][0] + lo0) = sb0;
            *(ushort8*)((char*)&Bls[nxt][0] + lo1) = sb1;
            __syncthreads();
        }
    }

#pragma unroll
    for (int mi = 0; mi < 4; mi++)
#pragma unroll
        for (int ni = 0; ni < 4; ni++) {
            const int rowb = bm + wm * 64 + mi * 16 + l4 * 4;
            const int colg = bn + wn * 64 + ni * 16 + l15;
#pragma unroll
            for (int r = 0; r < 4; r++) {
                const float v = acc[mi][ni][r];
                const int rowg = rowb + r;
                if constexpr (BHSD) {
                    const int b = rowg >> 11, s = rowg & 2047;
                    const int h = colg >> 6,  d = colg & 63;
                    outB[((size_t)(b * NHEAD + h) * SEQ + s) * HDIM + d] = f2bf(v);
                } else {
                    outF[(size_t)rowg * D_MODEL + colg] = v;
                }
            }
        }
}

__global__ __launch_bounds__(256) void k_gemm_qkv(
    const u16* __restrict__ xb,
    const u16* __restrict__ wq, const u16* __restrict__ wk, const u16* __restrict__ wv,
    u16* __restrict__ Qb, u16* __restrict__ Kb, u16* __restrict__ Vb)
{
    const int z = blockIdx.z;
    const u16* W = (z == 0) ? wq : (z == 1) ? wk : wv;
    u16*       O = (z == 0) ? Qb : (z == 1) ? Kb : Vb;
    gemm_body<true>(xb, W, O, nullptr, blockIdx.y * 128, blockIdx.x * 128);
}

__global__ __launch_bounds__(256) void k_gemm_o(
    const u16* __restrict__ yb, const u16* __restrict__ wo, float* __restrict__ out)
{
    gemm_body<false>(yb, wo, nullptr, out, blockIdx.y * 128, blockIdx.x * 128);
}

// ---------------------------------------------------------------------------
// RoPE in place on Q (z=0, also folds 1/sqrt(d)=0.125) and K (z=1).
// pair p of head dim: out[2p]   = x[2p]*cos - x[2p+1]*sin
//                     out[2p+1] = x[2p]*sin + x[2p+1]*cos
// angle = pos * theta^(-p/32),  theta=1e4 -> exp2(-p*log2(1e4)/32)
// ---------------------------------------------------------------------------
__global__ __launch_bounds__(256) void k_rope(
    u16* __restrict__ Qb, u16* __restrict__ Kb, const int* __restrict__ pos)
{
    const int z = blockIdx.y;
    u32* T = (u32*)(z ? Kb : Qb);
    const float scale = z ? 1.0f : 0.125f;
    const int idx = blockIdx.x * 256 + threadIdx.x;    // (bh*2048+s)*32+p
    const int p = idx & 31;
    const int s = (idx >> 5) & 2047;
    const float ps  = (float)pos[s];
    const float ang = ps * exp2f(-(float)p * 0.41524101186092435f);
    float sn, cs;
    sincosf(ang, &sn, &cs);
    const u32 v = T[idx];
    const float x0 = bf2f((u16)(v & 0xffffu));
    const float x1 = bf2f((u16)(v >> 16));
    const float r0a = (x0 * cs - x1 * sn) * scale;
    const float r1a = (x0 * sn + x1 * cs) * scale;
    T[idx] = (u32)f2bf(r0a) | ((u32)f2bf(r1a) << 16);
}

// ---------------------------------------------------------------------------
// Causal flash attention. Block = 4 waves x 32 queries = 128 q per (b,h).
// K tile [64 keys][64 dims] in LDS (swizzled); V staged transposed
// Vt[dim][key] (swizzled) so PV B-frags are contiguous b128 reads.
// Online softmax per query row via 16-lane shfl_xor reductions.
// ---------------------------------------------------------------------------
__global__ __launch_bounds__(256) void k_attn(
    const u16* __restrict__ Qb, const u16* __restrict__ Kb,
    const u16* __restrict__ Vb, u16* __restrict__ Yb)
{
    __shared__ u16 Kls[64 * 64];
    __shared__ u16 Vtls[64 * 64];
    __shared__ u16 Pls[4][32 * 64];
    const int tid  = threadIdx.x;
    const int lane = tid & 63, wv = tid >> 6;
    const int l15  = lane & 15, l4 = lane >> 4;
    const int bh    = blockIdx.x;           // b*16+h
    const int qbase = blockIdx.y * 128;
    const int qw    = qbase + wv * 32;      // wave's first query
    const size_t base = (size_t)bh * SEQ * HDIM;
    const u16* Qg = Qb + base;
    const u16* Kg = Kb + base;
    const u16* Vg = Vb + base;

    // Q fragments (scale already folded in by k_rope)
    bf16x8 qf[2][2];
#pragma unroll
    for (int mt = 0; mt < 2; mt++)
#pragma unroll
        for (int ks = 0; ks < 2; ks++)
            qf[mt][ks] = as_bf(*(const ushort8*)(
                Qg + (size_t)(qw + mt * 16 + l15) * HDIM + ks * 32 + l4 * 8));

    const f32x4 zz = {0.f, 0.f, 0.f, 0.f};
    f32x4 acc[2][4];
    float mst[2][4], lst[2][4];
#pragma unroll
    for (int mt = 0; mt < 2; mt++) {
#pragma unroll
        for (int n = 0; n < 4; n++) acc[mt][n] = zz;
#pragma unroll
        for (int r = 0; r < 4; r++) { mst[mt][r] = -1e30f; lst[mt][r] = 0.f; }
    }

    const int cA = tid, cB = tid + 256;
    const int kr0 = cA >> 3, kp0 = cA & 7, kr1 = cB >> 3, kp1 = cB & 7;
    const int vk0 = cA & 63, vd0 = cA >> 6, vk1 = cB & 63, vd1 = cB >> 6;

    const int nkb = qbase / 64 + 2;
    for (int kb = 0; kb < nkb; ++kb) {
        const int kbb = kb * 64;
        // --- stage K (row-major, swizzled) and V (transposed, swizzled) ---
        ushort8 tk0 = *(const ushort8*)(Kg + (size_t)(kbb + kr0) * HDIM + kp0 * 8);
        ushort8 tk1 = *(const ushort8*)(Kg + (size_t)(kbb + kr1) * HDIM + kp1 * 8);
        ushort8 tv0 = *(const ushort8*)(Vg + (size_t)(kbb + vk0) * HDIM + vd0 * 8);
        ushort8 tv1 = *(const ushort8*)(Vg + (size_t)(kbb + vk1) * HDIM + vd1 * 8);
        *(ushort8*)((char*)Kls + kr0 * 128 + ((kp0 * 16) ^ ((kr0 & 7) << 4))) = tk0;
        *(ushort8*)((char*)Kls + kr1 * 128 + ((kp1 * 16) ^ ((kr1 & 7) << 4))) = tk1;
#pragma unroll
        for (int j = 0; j < 8; j++) {
            const int d0 = vd0 * 8 + j, d1 = vd1 * 8 + j;
            *((u16*)((char*)Vtls + d0 * 128 + ((vk0 * 2) ^ ((d0 & 7) << 4)))) = tv0[j];
            *((u16*)((char*)Vtls + d1 * 128 + ((vk1 * 2) ^ ((d1 & 7) << 4)))) = tv1[j];
        }
        __syncthreads();

        if (kbb <= qw + 31) {   // wave-uniform: any of this wave's queries live?
            // --- S = Q K^T ---
            bf16x8 kf[4][2];
#pragma unroll
            for (int nt = 0; nt < 4; nt++)
#pragma unroll
                for (int ks = 0; ks < 2; ks++) {
                    const int row = nt * 16 + l15;
                    kf[nt][ks] = as_bf(*(const ushort8*)((const char*)Kls +
                        row * 128 + ((ks * 64 + l4 * 16) ^ ((row & 7) << 4))));
                }
            f32x4 sfr[2][4];
#pragma unroll
            for (int mt = 0; mt < 2; mt++)
#pragma unroll
                for (int nt = 0; nt < 4; nt++) {
                    f32x4 sv = zz;
                    sv = mfma16(qf[mt][0], kf[nt][0], sv);
                    sv = mfma16(qf[mt][1], kf[nt][1], sv);
                    sfr[mt][nt] = sv;
                }

            // --- mask + online softmax ---
#pragma unroll
            for (int mt = 0; mt < 2; mt++) {
                const int q0 = qw + mt * 16 + l4 * 4;  // + r
#pragma unroll
                for (int nt = 0; nt < 4; nt++) {
                    const int key = kbb + nt * 16 + l15;
#pragma unroll
                    for (int r = 0; r < 4; r++)
                        sfr[mt][nt][r] = (key <= q0 + r) ? sfr[mt][nt][r] : -1e30f;
                }
                float rmax[4];
#pragma unroll
                for (int r = 0; r < 4; r++) {
                    float m = fmaxf(fmaxf(sfr[mt][0][r], sfr[mt][1][r]),
                                    fmaxf(sfr[mt][2][r], sfr[mt][3][r]));
#pragma unroll
                    for (int off = 1; off < 16; off <<= 1)
                        m = fmaxf(m, __shfl_xor(m, off));
                    rmax[r] = m;
                }
                float sf[4];
#pragma unroll
                for (int r = 0; r < 4; r++) {
                    const float mnew = fmaxf(mst[mt][r], rmax[r]);
                    sf[r] = __expf(mst[mt][r] - mnew);
                    mst[mt][r] = mnew;
                }
                float psum[4] = {0.f, 0.f, 0.f, 0.f};
#pragma unroll
                for (int nt = 0; nt < 4; nt++) {
#pragma unroll
                    for (int r = 0; r < 4; r++) {
                        const float pv = __expf(sfr[mt][nt][r] - mst[mt][r]);
                        psum[r] += pv;
                        const int prow = mt * 16 + l4 * 4 + r;
                        const int pcol = nt * 16 + l15;
                        *((u16*)((char*)&Pls[wv][0] + prow * 128 +
                                 ((pcol * 2) ^ ((prow & 7) << 4)))) = f2bf(pv);
                    }
                }
#pragma unroll
                for (int r = 0; r < 4; r++) {
                    float s = psum[r];
#pragma unroll
                    for (int off = 1; off < 16; off <<= 1) s += __shfl_xor(s, off);
                    lst[mt][r] = lst[mt][r] * sf[r] + s;
                }
#pragma unroll
                for (int nd = 0; nd < 4; nd++)
#pragma unroll
                    for (int r = 0; r < 4; r++) acc[mt][nd][r] *= sf[r];
            }

            // --- O += P V ---
            bf16x8 vf[4][2];
#pragma unroll
            for (int nd = 0; nd < 4; nd++)
#pragma unroll
                for (int ks = 0; ks < 2; ks++) {
                    const int row = nd * 16 + l15;
                    vf[nd][ks] = as_bf(*(const ushort8*)((const char*)Vtls +
                        row * 128 + ((ks * 64 + l4 * 16) ^ ((row & 7) << 4))));
                }
#pragma unroll
            for (int mt = 0; mt < 2; mt++) {
                bf16x8 pf[2];
#pragma unroll
                for (int ks = 0; ks < 2; ks++) {
                    const int row = mt * 16 + l15;
                    pf[ks] = as_bf(*(const ushort8*)((const char*)&Pls[wv][0] +
                        row * 128 + ((ks * 64 + l4 * 16) ^ ((row & 7) << 4))));
                }
#pragma unroll
                for (int nd = 0; nd < 4; nd++) {
                    acc[mt][nd] = mfma16(pf[0], vf[nd][0], acc[mt][nd]);
                    acc[mt][nd] = mfma16(pf[1], vf[nd][1], acc[mt][nd]);
                }
            }
        }
        __syncthreads();
    }

    // --- epilogue: y[token][h*64+d] = acc / l ---
    const int b = bh >> 4, h = bh & 15;
#pragma unroll
    for (int mt = 0; mt < 2; mt++)
#pragma unroll
        for (int nd = 0; nd < 4; nd++)
#pragma unroll
            for (int r = 0; r < 4; r++) {
                const int q = qw + mt * 16 + l4 * 4 + r;
                const int d = nd * 16 + l15;
                const float v = acc[mt][nd][r] / lst[mt][r];
                Yb[(size_t)(b * SEQ + q) * D_MODEL + h * HDIM + d] = f2bf(v);
            }
}

// ---------------------------------------------------------------------------
extern "C" void kernel_launch(void* const* d_in, const int* in_sizes, int n_in,
                              void* d_out, int out_size, void* d_ws, size_t ws_size,
                              hipStream_t stream)
{
    const float* x  = (const float*)d_in[0];
    const float* wq = (const float*)d_in[1];
    const float* wk = (const float*)d_in[2];
    const float* wv = (const float*)d_in[3];
    const float* wo = (const float*)d_in[4];
    const int*  pos = (const int*)d_in[5];
    float* out = (float*)d_out;

    // workspace layout (bf16 elements):
    // [x 4M | wq 1M | wk 1M | wv 1M | wo 1M | Q 4M | K 4M | V 4M] = 40 MiB
    // y (attention output) aliases x (x is dead after the QKV GEMM).
    if (ws_size < (size_t)41943040) return;
    u16* xb  = (u16*)d_ws;
    u16* wqb = xb  + (size_t)4 * SEG;
    u16* wkb = wqb + SEG;
    u16* wvb = wkb + SEG;
    u16* wob = wvb + SEG;
    u16* Qb  = wob + SEG;
    u16* Kb  = Qb  + (size_t)4 * SEG;
    u16* Vb  = Kb  + (size_t)4 * SEG;
    u16* Yb  = xb;

    k_cvt     <<<dim3(512, 1, 8), 256, 0, stream>>>(x, wq, wk, wv, wo, xb);
    k_gemm_qkv<<<dim3(8, 32, 3),  256, 0, stream>>>(xb, wqb, wkb, wvb, Qb, Kb, Vb);
    k_rope    <<<dim3(8192, 2),   256, 0, stream>>>(Qb, Kb, pos);
    k_attn    <<<dim3(32, 16),    256, 0, stream>>>(Qb, Kb, Vb, Yb);
    k_gemm_o  <<<dim3(8, 32),     256, 0, stream>>>(Yb, wob, out);
}

// Round 4
// 153.882 us; speedup vs baseline: 1.1931x; 1.1917x over previous
//
#include <hip/hip_runtime.h>

// ---------------------------------------------------------------------------
// MultiHeadSelfAttentionWithRoPE  (B=2, S=2048, D=1024, H=16, d=64, causal)
// Pipeline: cvt(fp32->bf16) -> QKV gemm (MFMA bf16) -> RoPE -> flash attn
//           (MFMA bf16, in-register P, online softmax) -> O gemm (fp32 out)
// ---------------------------------------------------------------------------

typedef unsigned short u16;
typedef unsigned int   u32;
typedef u16    ushort8 __attribute__((ext_vector_type(8)));
typedef u16    u16x4   __attribute__((ext_vector_type(4)));
typedef short  s16x4   __attribute__((ext_vector_type(4)));
typedef __bf16 bf16x8  __attribute__((ext_vector_type(8)));
typedef float  f32x4   __attribute__((ext_vector_type(4)));

#define D_MODEL 1024
#define SEQ     2048
#define NHEAD   16
#define HDIM    64
#define NTOK    4096   // B*S
#define SEG     1048576

__device__ __forceinline__ u16 f2bf(float f) {        // RNE fp32->bf16
    u32 u = __builtin_bit_cast(u32, f);
    u32 r = (u + 0x7FFFu + ((u >> 16) & 1u)) >> 16;
    return (u16)r;
}
__device__ __forceinline__ float bf2f(u16 h) {
    return __builtin_bit_cast(float, (u32)h << 16);
}
__device__ __forceinline__ bf16x8 as_bf(ushort8 v) {
    return __builtin_bit_cast(bf16x8, v);
}
__device__ __forceinline__ f32x4 mfma16(bf16x8 a, bf16x8 b, f32x4 c) {
    return __builtin_amdgcn_mfma_f32_16x16x32_bf16(a, b, c, 0, 0, 0);
}

// ---------------------------------------------------------------------------
// fp32 -> bf16 conversion: z<4 quarters of x, z=4..7 -> W_Q,W_K,W_V,W_O
// ---------------------------------------------------------------------------
__global__ __launch_bounds__(256) void k_cvt(
    const float* __restrict__ x,  const float* __restrict__ wq,
    const float* __restrict__ wk, const float* __restrict__ wv,
    const float* __restrict__ wo, u16* __restrict__ dst0)
{
    const int z = blockIdx.z;
    const float* src; u16* dst;
    if      (z < 4)  { src = x + (size_t)z * SEG; dst = dst0 + (size_t)z * SEG; }
    else if (z == 4) { src = wq; dst = dst0 + (size_t)4 * SEG; }
    else if (z == 5) { src = wk; dst = dst0 + (size_t)5 * SEG; }
    else if (z == 6) { src = wv; dst = dst0 + (size_t)6 * SEG; }
    else             { src = wo; dst = dst0 + (size_t)7 * SEG; }
    const size_t i = ((size_t)blockIdx.x * 256 + threadIdx.x) * 8;
    f32x4 f0 = *(const f32x4*)(src + i);
    f32x4 f1 = *(const f32x4*)(src + i + 4);
    ushort8 o;
    o[0]=f2bf(f0[0]); o[1]=f2bf(f0[1]); o[2]=f2bf(f0[2]); o[3]=f2bf(f0[3]);
    o[4]=f2bf(f1[0]); o[5]=f2bf(f1[1]); o[6]=f2bf(f1[2]); o[7]=f2bf(f1[3]);
    *(ushort8*)(dst + i) = o;
}

// ---------------------------------------------------------------------------
// NT GEMM core: C[M,N] = A[M,K] * W[N,K]^T, K=1024, 128x128 block tile,
// 4 waves (2x2), each 64x64 via 4x4 mfma_16x16x32 fragments, BK=32,
// reg-staged double-buffered LDS with (row&3)<<4 XOR swizzle.
// ---------------------------------------------------------------------------
template<bool BHSD>
__device__ __forceinline__ void gemm_body(
    const u16* __restrict__ A, const u16* __restrict__ W,
    u16* __restrict__ outB, float* __restrict__ outF, int bm, int bn)
{
    __shared__ u16 Als[2][128 * 32];
    __shared__ u16 Bls[2][128 * 32];
    const int tid  = threadIdx.x;
    const int lane = tid & 63;
    const int wv   = tid >> 6;
    const int wm   = wv >> 1, wn = wv & 1;
    const int l15  = lane & 15, l4 = lane >> 4;

    const int c0 = tid, c1 = tid + 256;
    const int r0 = c0 >> 2, p0 = c0 & 3;
    const int r1 = c1 >> 2, p1 = c1 & 3;
    const u16* gA0 = A + (size_t)(bm + r0) * D_MODEL + p0 * 8;
    const u16* gA1 = A + (size_t)(bm + r1) * D_MODEL + p1 * 8;
    const u16* gB0 = W + (size_t)(bn + r0) * D_MODEL + p0 * 8;
    const u16* gB1 = W + (size_t)(bn + r1) * D_MODEL + p1 * 8;
    const int lo0 = r0 * 64 + ((p0 * 16) ^ ((r0 & 3) << 4));
    const int lo1 = r1 * 64 + ((p1 * 16) ^ ((r1 & 3) << 4));

    const f32x4 zz = {0.f, 0.f, 0.f, 0.f};
    f32x4 acc[4][4];
#pragma unroll
    for (int i = 0; i < 4; i++)
#pragma unroll
        for (int j = 0; j < 4; j++) acc[i][j] = zz;

    ushort8 sa0 = *(const ushort8*)gA0;
    ushort8 sa1 = *(const ushort8*)gA1;
    ushort8 sb0 = *(const ushort8*)gB0;
    ushort8 sb1 = *(const ushort8*)gB1;
    *(ushort8*)((char*)&Als[0][0] + lo0) = sa0;
    *(ushort8*)((char*)&Als[0][0] + lo1) = sa1;
    *(ushort8*)((char*)&Bls[0][0] + lo0) = sb0;
    *(ushort8*)((char*)&Bls[0][0] + lo1) = sb1;
    __syncthreads();

    for (int t = 0; t < 32; ++t) {
        const int cur = t & 1;
        if (t < 31) {
            const int k0 = (t + 1) * 32;
            sa0 = *(const ushort8*)(gA0 + k0);
            sa1 = *(const ushort8*)(gA1 + k0);
            sb0 = *(const ushort8*)(gB0 + k0);
            sb1 = *(const ushort8*)(gB1 + k0);
        }
        bf16x8 af[4], bfr[4];
#pragma unroll
        for (int mi = 0; mi < 4; mi++) {
            const int row = wm * 64 + mi * 16 + l15;
            af[mi] = as_bf(*(const ushort8*)((const char*)&Als[cur][0] +
                         row * 64 + ((l4 * 16) ^ ((row & 3) << 4))));
        }
#pragma unroll
        for (int ni = 0; ni < 4; ni++) {
            const int row = wn * 64 + ni * 16 + l15;
            bfr[ni] = as_bf(*(const ushort8*)((const char*)&Bls[cur][0] +
                          row * 64 + ((l4 * 16) ^ ((row & 3) << 4))));
        }
#pragma unroll
        for (int mi = 0; mi < 4; mi++)
#pragma unroll
            for (int ni = 0; ni < 4; ni++)
                acc[mi][ni] = mfma16(af[mi], bfr[ni], acc[mi][ni]);
        __syncthreads();
        if (t < 31) {
            const int nxt = cur ^ 1;
            *(ushort8*)((char*)&Als[nxt][0] + lo0) = sa0;
            *(ushort8*)((char*)&Als[nxt][0] + lo1) = sa1;
            *(ushort8*)((char*)&Bls[nxt][0] + lo0) = sb0;
            *(ushort8*)((char*)&Bls[nxt][0] + lo1) = sb1;
            __syncthreads();
        }
    }

#pragma unroll
    for (int mi = 0; mi < 4; mi++)
#pragma unroll
        for (int ni = 0; ni < 4; ni++) {
            const int rowb = bm + wm * 64 + mi * 16 + l4 * 4;
            const int colg = bn + wn * 64 + ni * 16 + l15;
#pragma unroll
            for (int r = 0; r < 4; r++) {
                const float v = acc[mi][ni][r];
                const int rowg = rowb + r;
                if constexpr (BHSD) {
                    const int b = rowg >> 11, s = rowg & 2047;
                    const int h = colg >> 6,  d = colg & 63;
                    outB[((size_t)(b * NHEAD + h) * SEQ + s) * HDIM + d] = f2bf(v);
                } else {
                    outF[(size_t)rowg * D_MODEL + colg] = v;
                }
            }
        }
}

__global__ __launch_bounds__(256) void k_gemm_qkv(
    const u16* __restrict__ xb,
    const u16* __restrict__ wq, const u16* __restrict__ wk, const u16* __restrict__ wv,
    u16* __restrict__ Qb, u16* __restrict__ Kb, u16* __restrict__ Vb)
{
    const int z = blockIdx.z;
    const u16* W = (z == 0) ? wq : (z == 1) ? wk : wv;
    u16*       O = (z == 0) ? Qb : (z == 1) ? Kb : Vb;
    gemm_body<true>(xb, W, O, nullptr, blockIdx.y * 128, blockIdx.x * 128);
}

__global__ __launch_bounds__(256) void k_gemm_o(
    const u16* __restrict__ yb, const u16* __restrict__ wo, float* __restrict__ out)
{
    gemm_body<false>(yb, wo, nullptr, out, blockIdx.y * 128, blockIdx.x * 128);
}

// ---------------------------------------------------------------------------
// RoPE in place on Q (z=0, folds 1/sqrt(d)*log2(e) so attn can use exp2)
// and K (z=1).
// ---------------------------------------------------------------------------
__global__ __launch_bounds__(256) void k_rope(
    u16* __restrict__ Qb, u16* __restrict__ Kb, const int* __restrict__ pos)
{
    const int z = blockIdx.y;
    u32* T = (u32*)(z ? Kb : Qb);
    // Q scale = 0.125 * log2(e): scores end up in base-2 units for exp2f.
    const float scale = z ? 1.0f : 0.125f * 1.44269504088896340736f;
    const int idx = blockIdx.x * 256 + threadIdx.x;    // (bh*2048+s)*32+p
    const int p = idx & 31;
    const int s = (idx >> 5) & 2047;
    const float ps  = (float)pos[s];
    const float ang = ps * exp2f(-(float)p * 0.41524101186092435f);
    float sn, cs;
    sincosf(ang, &sn, &cs);
    const u32 v = T[idx];
    const float x0 = bf2f((u16)(v & 0xffffu));
    const float x1 = bf2f((u16)(v >> 16));
    const float r0a = (x0 * cs - x1 * sn) * scale;
    const float r1a = (x0 * sn + x1 * cs) * scale;
    T[idx] = (u32)f2bf(r0a) | ((u32)f2bf(r1a) << 16);
}

// ---------------------------------------------------------------------------
// Causal flash attention, in-register P.
//   St = mfma_16x16x32(A=K-rows, B=Q-rows)  -> lane holds P[q=l15][k=l4*4+r]
//   which IS the B-frag layout of mfma_16x16x16bf16_1k. PV computes
//   O^T = mfma(A=V^T-frag, B=P) so C/D rows are d and cols are q=l15 --
//   softmax state (m,l per q) stays lane-local, zero P LDS traffic.
// Double-buffered K/Vt LDS, single barrier per tile, async reg staging.
// Longest q-tiles dispatch first (LPT balance).
// ---------------------------------------------------------------------------
__global__ __launch_bounds__(256) void k_attn(
    const u16* __restrict__ Qb, const u16* __restrict__ Kb,
    const u16* __restrict__ Vb, u16* __restrict__ Yb)
{
    __shared__ u16 Kls[2][64 * 64];    // [buf][k-row][d]  swizzled ^((row&7)<<4)
    __shared__ u16 Vtls[2][64 * 64];   // [buf][d-row][k]  swizzled ^((d&7)<<4)
    const int tid  = threadIdx.x;
    const int lane = tid & 63, wv = tid >> 6;
    const int l15  = lane & 15, l4 = lane >> 4;
    const int bh    = blockIdx.x;            // b*16+h
    const int qt    = 15 - blockIdx.y;       // longest blocks dispatch first
    const int qbase = qt * 128;
    const int qw    = qbase + wv * 32;       // wave's first query
    const size_t base = (size_t)bh * SEQ * HDIM;
    const u16* Qg = Qb + base;
    const u16* Kg = Kb + base;
    const u16* Vg = Vb + base;

    // Q B-frags (scale folded in by k_rope): B[n=q=l15][kk=d=l4*8+i]
    bf16x8 qf[2][2];
#pragma unroll
    for (int mt = 0; mt < 2; mt++)
#pragma unroll
        for (int ks = 0; ks < 2; ks++)
            qf[mt][ks] = as_bf(*(const ushort8*)(
                Qg + (size_t)(qw + mt * 16 + l15) * HDIM + ks * 32 + l4 * 8));

    const f32x4 zz = {0.f, 0.f, 0.f, 0.f};
    f32x4 acc[2][4];                 // O^T: lane holds [d=nd*16+l4*4+r][q=l15]
    float mst[2], lst[2];
#pragma unroll
    for (int mt = 0; mt < 2; mt++) {
#pragma unroll
        for (int n = 0; n < 4; n++) acc[mt][n] = zz;
        mst[mt] = -1e30f; lst[mt] = 0.f;
    }

    // staging: K 512x16B chunks, V 512x16B chunks, 2 each per thread
    const int kr0 = tid >> 3, kp0 = tid & 7;       // K rows 0..31
    const int kr1 = kr0 + 32, kp1 = kp0;           // K rows 32..63
    const int vk0 = tid & 63, vd0 = tid >> 6;      // V: key, d-octet 0..3
    const int vd1 = vd0 + 4;                       // d-octet 4..7
    const int klo0 = kr0 * 128 + ((kp0 * 16) ^ ((kr0 & 7) << 4));
    const int klo1 = kr1 * 128 + ((kp1 * 16) ^ ((kr1 & 7) << 4));

    const int nkb = 2 * qt + 2;

    // prologue: stage tile 0
    ushort8 tk0 = *(const ushort8*)(Kg + (size_t)kr0 * HDIM + kp0 * 8);
    ushort8 tk1 = *(const ushort8*)(Kg + (size_t)kr1 * HDIM + kp1 * 8);
    ushort8 tv0 = *(const ushort8*)(Vg + (size_t)vk0 * HDIM + vd0 * 8);
    ushort8 tv1 = *(const ushort8*)(Vg + (size_t)vk0 * HDIM + vd1 * 8);
    *(ushort8*)((char*)&Kls[0][0] + klo0) = tk0;
    *(ushort8*)((char*)&Kls[0][0] + klo1) = tk1;
#pragma unroll
    for (int j = 0; j < 8; j++) {
        const int d0 = vd0 * 8 + j, d1 = vd1 * 8 + j;
        *((u16*)((char*)&Vtls[0][0] + d0 * 128 + ((vk0 * 2) ^ ((d0 & 7) << 4)))) = tv0[j];
        *((u16*)((char*)&Vtls[0][0] + d1 * 128 + ((vk0 * 2) ^ ((d1 & 7) << 4)))) = tv1[j];
    }
    __syncthreads();

    for (int kb = 0; kb < nkb; ++kb) {
        const int cur = kb & 1;
        const int kbb = kb * 64;
        // issue next-tile global loads early (latency hides under compute)
        if (kb + 1 < nkb) {
            const size_t ro = (size_t)(kbb + 64) * HDIM;
            tk0 = *(const ushort8*)(Kg + ro + (size_t)kr0 * HDIM + kp0 * 8);
            tk1 = *(const ushort8*)(Kg + ro + (size_t)kr1 * HDIM + kp1 * 8);
            tv0 = *(const ushort8*)(Vg + ro + (size_t)vk0 * HDIM + vd0 * 8);
            tv1 = *(const ushort8*)(Vg + ro + (size_t)vk0 * HDIM + vd1 * 8);
        }

        if (kbb <= qw + 31) {   // wave-uniform liveness
            // --- K A-frags: A[m=k-row=l15][kk=d=l4*8+i] ---
            bf16x8 kf[4][2];
#pragma unroll
            for (int nt = 0; nt < 4; nt++)
#pragma unroll
                for (int ks = 0; ks < 2; ks++) {
                    const int row = nt * 16 + l15;
                    kf[nt][ks] = as_bf(*(const ushort8*)((const char*)&Kls[cur][0] +
                        row * 128 + ((ks * 64 + l4 * 16) ^ ((row & 7) << 4))));
                }

            s16x4 pb[2][4];
#pragma unroll
            for (int mt = 0; mt < 2; mt++) {
                // St = K·Q^T : lane holds S[k=kbb+nt*16+l4*4+r][q=qw+mt*16+l15]
                f32x4 st[4];
#pragma unroll
                for (int nt = 0; nt < 4; nt++) {
                    f32x4 sv = mfma16(kf[nt][0], qf[mt][0], zz);
                    st[nt]   = mfma16(kf[nt][1], qf[mt][1], sv);
                }
                const int qg = qw + mt * 16 + l15;
                if (kbb + 63 > qw + mt * 16) {   // masking needed for this mt
#pragma unroll
                    for (int nt = 0; nt < 4; nt++)
#pragma unroll
                        for (int r = 0; r < 4; r++) {
                            const int kg = kbb + nt * 16 + l4 * 4 + r;
                            st[nt][r] = (kg <= qg) ? st[nt][r] : -1e30f;
                        }
                }
                // row max: 16 in-lane values + 2 cross-lane shuffles
                float m = fmaxf(
                    fmaxf(fmaxf(fmaxf(st[0][0], st[0][1]), fmaxf(st[0][2], st[0][3])),
                          fmaxf(fmaxf(st[1][0], st[1][1]), fmaxf(st[1][2], st[1][3]))),
                    fmaxf(fmaxf(fmaxf(st[2][0], st[2][1]), fmaxf(st[2][2], st[2][3])),
                          fmaxf(fmaxf(st[3][0], st[3][1]), fmaxf(st[3][2], st[3][3]))));
                m = fmaxf(m, __shfl_xor(m, 16));
                m = fmaxf(m, __shfl_xor(m, 32));
                const float mo = mst[mt];
                if (!__all(m - mo <= 8.0f)) {     // defer-max (T13, base-2 units)
                    const float mn = fmaxf(mo, m);
                    const float sf = exp2f(mo - mn);
                    mst[mt] = mn;
                    lst[mt] *= sf;
#pragma unroll
                    for (int nd = 0; nd < 4; nd++) acc[mt][nd] *= sf;
                }
                const float mm = mst[mt];
                float ps = 0.f;
#pragma unroll
                for (int nt = 0; nt < 4; nt++) {
                    s16x4 pv;
#pragma unroll
                    for (int r = 0; r < 4; r++) {
                        const float p = exp2f(st[nt][r] - mm);
                        ps += p;
                        pv[r] = (short)f2bf(p);
                    }
                    pb[mt][nt] = pv;
                }
                ps += __shfl_xor(ps, 16);
                ps += __shfl_xor(ps, 32);
                lst[mt] += ps;
            }

            // --- O^T += V^T · P : A=V^T-frag (b64 from Vt), B=P (in reg) ---
#pragma unroll
            for (int nt = 0; nt < 4; nt++) {
                const int kk2 = (nt * 16 + l4 * 4) * 2;
#pragma unroll
                for (int nd = 0; nd < 4; nd++) {
                    const int d = nd * 16 + l15;
                    const s16x4 va = *(const s16x4*)((const char*)&Vtls[cur][0] +
                        d * 128 + (kk2 ^ ((d & 7) << 4)));
                    acc[0][nd] = __builtin_amdgcn_mfma_f32_16x16x16bf16_1k(
                        va, pb[0][nt], acc[0][nd], 0, 0, 0);
                    acc[1][nd] = __builtin_amdgcn_mfma_f32_16x16x16bf16_1k(
                        va, pb[1][nt], acc[1][nd], 0, 0, 0);
                }
            }
        }

        // write next tile into the other buffer (no race with cur readers)
        if (kb + 1 < nkb) {
            const int nxt = cur ^ 1;
            *(ushort8*)((char*)&Kls[nxt][0] + klo0) = tk0;
            *(ushort8*)((char*)&Kls[nxt][0] + klo1) = tk1;
#pragma unroll
            for (int j = 0; j < 8; j++) {
                const int d0 = vd0 * 8 + j, d1 = vd1 * 8 + j;
                *((u16*)((char*)&Vtls[nxt][0] + d0 * 128 + ((vk0 * 2) ^ ((d0 & 7) << 4)))) = tv0[j];
                *((u16*)((char*)&Vtls[nxt][0] + d1 * 128 + ((vk0 * 2) ^ ((d1 & 7) << 4)))) = tv1[j];
            }
        }
        __syncthreads();
    }

    // --- epilogue: lane holds O^T[d=nd*16+l4*4+r][q=l15]; write /lst ---
    const int b = bh >> 4, h = bh & 15;
#pragma unroll
    for (int mt = 0; mt < 2; mt++) {
        const float inv = 1.0f / lst[mt];
        const int q = qw + mt * 16 + l15;
#pragma unroll
        for (int nd = 0; nd < 4; nd++) {
            u16x4 o;
#pragma unroll
            for (int r = 0; r < 4; r++) o[r] = f2bf(acc[mt][nd][r] * inv);
            const int d = nd * 16 + l4 * 4;
            *(u16x4*)(Yb + (size_t)(b * SEQ + q) * D_MODEL + h * HDIM + d) = o;
        }
    }
}

// ---------------------------------------------------------------------------
extern "C" void kernel_launch(void* const* d_in, const int* in_sizes, int n_in,
                              void* d_out, int out_size, void* d_ws, size_t ws_size,
                              hipStream_t stream)
{
    const float* x  = (const float*)d_in[0];
    const float* wq = (const float*)d_in[1];
    const float* wk = (const float*)d_in[2];
    const float* wv = (const float*)d_in[3];
    const float* wo = (const float*)d_in[4];
    const int*  pos = (const int*)d_in[5];
    float* out = (float*)d_out;

    // workspace layout (bf16 elements):
    // [x 4M | wq 1M | wk 1M | wv 1M | wo 1M | Q 4M | K 4M | V 4M] = 40 MiB
    // y (attention output) aliases x (x is dead after the QKV GEMM).
    if (ws_size < (size_t)41943040) return;
    u16* xb  = (u16*)d_ws;
    u16* wqb = xb  + (size_t)4 * SEG;
    u16* wkb = wqb + SEG;
    u16* wvb = wkb + SEG;
    u16* wob = wvb + SEG;
    u16* Qb  = wob + SEG;
    u16* Kb  = Qb  + (size_t)4 * SEG;
    u16* Vb  = Kb  + (size_t)4 * SEG;
    u16* Yb  = xb;

    k_cvt     <<<dim3(512, 1, 8), 256, 0, stream>>>(x, wq, wk, wv, wo, xb);
    k_gemm_qkv<<<dim3(8, 32, 3),  256, 0, stream>>>(xb, wqb, wkb, wvb, Qb, Kb, Vb);
    k_rope    <<<dim3(8192, 2),   256, 0, stream>>>(Qb, Kb, pos);
    k_attn    <<<dim3(32, 16),    256, 0, stream>>>(Qb, Kb, Vb, Yb);
    k_gemm_o  <<<dim3(8, 32),     256, 0, stream>>>(Yb, wob, out);
}

// Round 5
// 135.958 us; speedup vs baseline: 1.3504x; 1.1318x over previous
//
#include <hip/hip_runtime.h>

// ---------------------------------------------------------------------------
// MultiHeadSelfAttentionWithRoPE  (B=2, S=2048, D=1024, H=16, d=64, causal)
// Pipeline: cvt(fp32->bf16) -> QKV gemm (MFMA bf16) -> RoPE -> flash attn
//           (MFMA bf16, in-register P, online softmax) -> O gemm (fp32 out)
// ---------------------------------------------------------------------------

typedef unsigned short u16;
typedef unsigned int   u32;
typedef u16    ushort8 __attribute__((ext_vector_type(8)));
typedef u16    u16x4   __attribute__((ext_vector_type(4)));
typedef short  s16x4   __attribute__((ext_vector_type(4)));
typedef __bf16 bf16x8  __attribute__((ext_vector_type(8)));
typedef float  f32x4   __attribute__((ext_vector_type(4)));

#define D_MODEL 1024
#define SEQ     2048
#define NHEAD   16
#define HDIM    64
#define NTOK    4096   // B*S
#define SEG     1048576

__device__ __forceinline__ u16 f2bf(float f) {        // RNE fp32->bf16
    u32 u = __builtin_bit_cast(u32, f);
    u32 r = (u + 0x7FFFu + ((u >> 16) & 1u)) >> 16;
    return (u16)r;
}
__device__ __forceinline__ float bf2f(u16 h) {
    return __builtin_bit_cast(float, (u32)h << 16);
}
__device__ __forceinline__ bf16x8 as_bf(ushort8 v) {
    return __builtin_bit_cast(bf16x8, v);
}
__device__ __forceinline__ f32x4 mfma16(bf16x8 a, bf16x8 b, f32x4 c) {
    return __builtin_amdgcn_mfma_f32_16x16x32_bf16(a, b, c, 0, 0, 0);
}

// ---------------------------------------------------------------------------
// fp32 -> bf16 conversion: z<4 quarters of x, z=4..7 -> W_Q,W_K,W_V,W_O
// ---------------------------------------------------------------------------
__global__ __launch_bounds__(256) void k_cvt(
    const float* __restrict__ x,  const float* __restrict__ wq,
    const float* __restrict__ wk, const float* __restrict__ wv,
    const float* __restrict__ wo, u16* __restrict__ dst0)
{
    const int z = blockIdx.z;
    const float* src; u16* dst;
    if      (z < 4)  { src = x + (size_t)z * SEG; dst = dst0 + (size_t)z * SEG; }
    else if (z == 4) { src = wq; dst = dst0 + (size_t)4 * SEG; }
    else if (z == 5) { src = wk; dst = dst0 + (size_t)5 * SEG; }
    else if (z == 6) { src = wv; dst = dst0 + (size_t)6 * SEG; }
    else             { src = wo; dst = dst0 + (size_t)7 * SEG; }
    const size_t i = ((size_t)blockIdx.x * 256 + threadIdx.x) * 8;
    f32x4 f0 = *(const f32x4*)(src + i);
    f32x4 f1 = *(const f32x4*)(src + i + 4);
    ushort8 o;
    o[0]=f2bf(f0[0]); o[1]=f2bf(f0[1]); o[2]=f2bf(f0[2]); o[3]=f2bf(f0[3]);
    o[4]=f2bf(f1[0]); o[5]=f2bf(f1[1]); o[6]=f2bf(f1[2]); o[7]=f2bf(f1[3]);
    *(ushort8*)(dst + i) = o;
}

// ---------------------------------------------------------------------------
// NT GEMM core: C[M,N] = A[M,K] * W[N,K]^T, K=1024, 128x128 block tile,
// 4 waves (2x2), each 64x64 via 4x4 mfma_16x16x32 fragments, BK=32,
// reg-staged double-buffered LDS with (row&3)<<4 XOR swizzle.
// ---------------------------------------------------------------------------
template<bool BHSD>
__device__ __forceinline__ void gemm_body(
    const u16* __restrict__ A, const u16* __restrict__ W,
    u16* __restrict__ outB, float* __restrict__ outF, int bm, int bn)
{
    __shared__ u16 Als[2][128 * 32];
    __shared__ u16 Bls[2][128 * 32];
    const int tid  = threadIdx.x;
    const int lane = tid & 63;
    const int wv   = tid >> 6;
    const int wm   = wv >> 1, wn = wv & 1;
    const int l15  = lane & 15, l4 = lane >> 4;

    const int c0 = tid, c1 = tid + 256;
    const int r0 = c0 >> 2, p0 = c0 & 3;
    const int r1 = c1 >> 2, p1 = c1 & 3;
    const u16* gA0 = A + (size_t)(bm + r0) * D_MODEL + p0 * 8;
    const u16* gA1 = A + (size_t)(bm + r1) * D_MODEL + p1 * 8;
    const u16* gB0 = W + (size_t)(bn + r0) * D_MODEL + p0 * 8;
    const u16* gB1 = W + (size_t)(bn + r1) * D_MODEL + p1 * 8;
    const int lo0 = r0 * 64 + ((p0 * 16) ^ ((r0 & 3) << 4));
    const int lo1 = r1 * 64 + ((p1 * 16) ^ ((r1 & 3) << 4));

    const f32x4 zz = {0.f, 0.f, 0.f, 0.f};
    f32x4 acc[4][4];
#pragma unroll
    for (int i = 0; i < 4; i++)
#pragma unroll
        for (int j = 0; j < 4; j++) acc[i][j] = zz;

    ushort8 sa0 = *(const ushort8*)gA0;
    ushort8 sa1 = *(const ushort8*)gA1;
    ushort8 sb0 = *(const ushort8*)gB0;
    ushort8 sb1 = *(const ushort8*)gB1;
    *(ushort8*)((char*)&Als[0][0] + lo0) = sa0;
    *(ushort8*)((char*)&Als[0][0] + lo1) = sa1;
    *(ushort8*)((char*)&Bls[0][0] + lo0) = sb0;
    *(ushort8*)((char*)&Bls[0][0] + lo1) = sb1;
    __syncthreads();

    for (int t = 0; t < 32; ++t) {
        const int cur = t & 1;
        if (t < 31) {
            const int k0 = (t + 1) * 32;
            sa0 = *(const ushort8*)(gA0 + k0);
            sa1 = *(const ushort8*)(gA1 + k0);
            sb0 = *(const ushort8*)(gB0 + k0);
            sb1 = *(const ushort8*)(gB1 + k0);
        }
        bf16x8 af[4], bfr[4];
#pragma unroll
        for (int mi = 0; mi < 4; mi++) {
            const int row = wm * 64 + mi * 16 + l15;
            af[mi] = as_bf(*(const ushort8*)((const char*)&Als[cur][0] +
                         row * 64 + ((l4 * 16) ^ ((row & 3) << 4))));
        }
#pragma unroll
        for (int ni = 0; ni < 4; ni++) {
            const int row = wn * 64 + ni * 16 + l15;
            bfr[ni] = as_bf(*(const ushort8*)((const char*)&Bls[cur][0] +
                          row * 64 + ((l4 * 16) ^ ((row & 3) << 4))));
        }
#pragma unroll
        for (int mi = 0; mi < 4; mi++)
#pragma unroll
            for (int ni = 0; ni < 4; ni++)
                acc[mi][ni] = mfma16(af[mi], bfr[ni], acc[mi][ni]);
        __syncthreads();
        if (t < 31) {
            const int nxt = cur ^ 1;
            *(ushort8*)((char*)&Als[nxt][0] + lo0) = sa0;
            *(ushort8*)((char*)&Als[nxt][0] + lo1) = sa1;
            *(ushort8*)((char*)&Bls[nxt][0] + lo0) = sb0;
            *(ushort8*)((char*)&Bls[nxt][0] + lo1) = sb1;
            __syncthreads();
        }
    }

#pragma unroll
    for (int mi = 0; mi < 4; mi++)
#pragma unroll
        for (int ni = 0; ni < 4; ni++) {
            const int rowb = bm + wm * 64 + mi * 16 + l4 * 4;
            const int colg = bn + wn * 64 + ni * 16 + l15;
#pragma unroll
            for (int r = 0; r < 4; r++) {
                const float v = acc[mi][ni][r];
                const int rowg = rowb + r;
                if constexpr (BHSD) {
                    const int b = rowg >> 11, s = rowg & 2047;
                    const int h = colg >> 6,  d = colg & 63;
                    outB[((size_t)(b * NHEAD + h) * SEQ + s) * HDIM + d] = f2bf(v);
                } else {
                    outF[(size_t)rowg * D_MODEL + colg] = v;
                }
            }
        }
}

__global__ __launch_bounds__(256) void k_gemm_qkv(
    const u16* __restrict__ xb,
    const u16* __restrict__ wq, const u16* __restrict__ wk, const u16* __restrict__ wv,
    u16* __restrict__ Qb, u16* __restrict__ Kb, u16* __restrict__ Vb)
{
    const int z = blockIdx.z;
    const u16* W = (z == 0) ? wq : (z == 1) ? wk : wv;
    u16*       O = (z == 0) ? Qb : (z == 1) ? Kb : Vb;
    gemm_body<true>(xb, W, O, nullptr, blockIdx.y * 128, blockIdx.x * 128);
}

__global__ __launch_bounds__(256) void k_gemm_o(
    const u16* __restrict__ yb, const u16* __restrict__ wo, float* __restrict__ out)
{
    gemm_body<false>(yb, wo, nullptr, out, blockIdx.y * 128, blockIdx.x * 128);
}

// ---------------------------------------------------------------------------
// RoPE in place on Q (z=0, folds 1/sqrt(d)*log2(e) so attn can use exp2)
// and K (z=1).
// ---------------------------------------------------------------------------
__global__ __launch_bounds__(256) void k_rope(
    u16* __restrict__ Qb, u16* __restrict__ Kb, const int* __restrict__ pos)
{
    const int z = blockIdx.y;
    u32* T = (u32*)(z ? Kb : Qb);
    // Q scale = 0.125 * log2(e): scores end up in base-2 units for exp2f.
    const float scale = z ? 1.0f : 0.125f * 1.44269504088896340736f;
    const int idx = blockIdx.x * 256 + threadIdx.x;    // (bh*2048+s)*32+p
    const int p = idx & 31;
    const int s = (idx >> 5) & 2047;
    const float ps  = (float)pos[s];
    const float ang = ps * exp2f(-(float)p * 0.41524101186092435f);
    float sn, cs;
    sincosf(ang, &sn, &cs);
    const u32 v = T[idx];
    const float x0 = bf2f((u16)(v & 0xffffu));
    const float x1 = bf2f((u16)(v >> 16));
    const float r0a = (x0 * cs - x1 * sn) * scale;
    const float r1a = (x0 * sn + x1 * cs) * scale;
    T[idx] = (u32)f2bf(r0a) | ((u32)f2bf(r1a) << 16);
}

// ---------------------------------------------------------------------------
// Causal flash attention, in-register P, QBLK=64 (1024 blocks -> 4 blocks/CU
// for latency hiding; every wave live on every tile; mask only on diagonal).
//   St = mfma_16x16x32(A=K-rows, B=Q-rows) -> lane holds P[k=l4*4+r][q=l15]
//   = B-frag of mfma_16x16x16bf16_1k. PV: O^T = mfma(A=V^T-frag, B=P).
// V^T stored with paired-nt within-row permutation so each PV A-frag pair is
// ONE ds_read_b128 in the XOR-swizzle pattern that measured 0 bank conflicts.
// Double-buffered K/Vt LDS, single barrier/tile, async reg staging, T5, T13.
// ---------------------------------------------------------------------------
__global__ __launch_bounds__(256, 4) void k_attn(
    const u16* __restrict__ Qb, const u16* __restrict__ Kb,
    const u16* __restrict__ Vb, u16* __restrict__ Yb)
{
    __shared__ u16 Kls[2][64 * 64];    // [buf][k-row][d]   swz ^((row&7)<<4)
    __shared__ u16 Vtls[2][64 * 64];   // [buf][d-row][perm(k)] swz ^((d&7)<<4)
    const int tid  = threadIdx.x;
    const int lane = tid & 63, wv = tid >> 6;
    const int l15  = lane & 15, l4 = lane >> 4;
    const int bh   = blockIdx.x;             // b*16+h
    const int qt   = 31 - blockIdx.y;        // longest blocks dispatch first
    const int qw   = qt * 64 + wv * 16;      // wave's first query
    const size_t base = (size_t)bh * SEQ * HDIM;
    const u16* Qg = Qb + base;
    const u16* Kg = Kb + base;
    const u16* Vg = Vb + base;

    // per-lane LDS read bases: addr = tile*2048 + rb[half]; same bases serve
    // K frags (half = ks) and Vt frags (half = nt2).
    const int sw  = (l15 & 7) << 4;
    const int rb0 = l15 * 128 + ((l4 * 16) ^ sw);
    const int rb1 = l15 * 128 + ((64 + l4 * 16) ^ sw);

    // Q B-frags (scale folded in by k_rope): B[n=q=l15][kk=d=l4*8+i]
    bf16x8 qf[2];
#pragma unroll
    for (int ks = 0; ks < 2; ks++)
        qf[ks] = as_bf(*(const ushort8*)(
            Qg + (size_t)(qw + l15) * HDIM + ks * 32 + l4 * 8));

    const f32x4 zz = {0.f, 0.f, 0.f, 0.f};
    f32x4 acc[4];                 // O^T: lane holds [d=nd*16+l4*4+r][q=l15]
    float mst = -1e30f, lst = 0.f;
#pragma unroll
    for (int n = 0; n < 4; n++) acc[n] = zz;

    // staging lane constants
    const int kr0 = tid >> 3, kp0 = tid & 7;       // K rows 0..31
    const int kr1 = kr0 + 32;                      // K rows 32..63
    const int vk0 = tid & 63, vd0 = tid >> 6;      // V: key, d-octet 0..3
    const int vd1 = vd0 + 4;                       // d-octet 4..7
    const int klo0 = kr0 * 128 + ((kp0 * 16) ^ ((kr0 & 7) << 4));
    const int klo1 = kr1 * 128 + ((kp0 * 16) ^ ((kr1 & 7) << 4));
    // Vt within-row u16 position of key k (paired-nt permutation), in bytes
    const int vpos2 = 2 * ((vk0 >> 5) * 32 + ((vk0 & 15) >> 2) * 8 +
                           ((vk0 >> 4) & 1) * 4 + (vk0 & 3));

    const int nkb = qt + 1;

    // prologue: stage tile 0
    ushort8 tk0 = *(const ushort8*)(Kg + (size_t)kr0 * HDIM + kp0 * 8);
    ushort8 tk1 = *(const ushort8*)(Kg + (size_t)kr1 * HDIM + kp0 * 8);
    ushort8 tv0 = *(const ushort8*)(Vg + (size_t)vk0 * HDIM + vd0 * 8);
    ushort8 tv1 = *(const ushort8*)(Vg + (size_t)vk0 * HDIM + vd1 * 8);
    *(ushort8*)((char*)&Kls[0][0] + klo0) = tk0;
    *(ushort8*)((char*)&Kls[0][0] + klo1) = tk1;
#pragma unroll
    for (int j = 0; j < 8; j++) {   // d&7 == j for both octets -> swz = j<<4
        *((u16*)((char*)&Vtls[0][0] + (vd0*8+j) * 128 + (vpos2 ^ (j << 4)))) = tv0[j];
        *((u16*)((char*)&Vtls[0][0] + (vd1*8+j) * 128 + (vpos2 ^ (j << 4)))) = tv1[j];
    }
    __syncthreads();

    for (int kb = 0; kb < nkb; ++kb) {
        const int cur = kb & 1;
        // issue next-tile global loads early (hide HBM/L2 under compute)
        if (kb + 1 < nkb) {
            const size_t ro = (size_t)(kb + 1) * 64 * HDIM;
            tk0 = *(const ushort8*)(Kg + ro + (size_t)kr0 * HDIM + kp0 * 8);
            tk1 = *(const ushort8*)(Kg + ro + (size_t)kr1 * HDIM + kp0 * 8);
            tv0 = *(const ushort8*)(Vg + ro + (size_t)vk0 * HDIM + vd0 * 8);
            tv1 = *(const ushort8*)(Vg + ro + (size_t)vk0 * HDIM + vd1 * 8);
        }

        // --- S^T = K·Q^T : lane holds S[k=kb*64+nt*16+l4*4+r][q=qw+l15] ---
        const char* Kbase = (const char*)&Kls[cur][0];
        bf16x8 kf[4][2];
#pragma unroll
        for (int nt = 0; nt < 4; nt++) {
            kf[nt][0] = as_bf(*(const ushort8*)(Kbase + nt * 2048 + rb0));
            kf[nt][1] = as_bf(*(const ushort8*)(Kbase + nt * 2048 + rb1));
        }
        f32x4 st[4];
        __builtin_amdgcn_s_setprio(1);
#pragma unroll
        for (int nt = 0; nt < 4; nt++) {
            f32x4 sv = mfma16(kf[nt][0], qf[0], zz);
            st[nt]   = mfma16(kf[nt][1], qf[1], sv);
        }
        __builtin_amdgcn_s_setprio(0);

        if (kb == qt) {               // diagonal tile: causal mask
            const int qg = qw + l15;
            const int kbb = kb * 64;
#pragma unroll
            for (int nt = 0; nt < 4; nt++)
#pragma unroll
                for (int r = 0; r < 4; r++) {
                    const int kg = kbb + nt * 16 + l4 * 4 + r;
                    st[nt][r] = (kg <= qg) ? st[nt][r] : -1e30f;
                }
        }

        // --- online softmax (per q-row; rows live on lanes l15, l4-split k) ---
        float m0 = fmaxf(fmaxf(st[0][0], st[0][1]), fmaxf(st[0][2], st[0][3]));
        float m1 = fmaxf(fmaxf(st[1][0], st[1][1]), fmaxf(st[1][2], st[1][3]));
        float m2 = fmaxf(fmaxf(st[2][0], st[2][1]), fmaxf(st[2][2], st[2][3]));
        float m3 = fmaxf(fmaxf(st[3][0], st[3][1]), fmaxf(st[3][2], st[3][3]));
        float m  = fmaxf(fmaxf(m0, m1), fmaxf(m2, m3));
        m = fmaxf(m, __shfl_xor(m, 16));
        m = fmaxf(m, __shfl_xor(m, 32));
        if (!__all(m - mst <= 8.0f)) {        // defer-max (T13, base-2 units)
            const float mn = fmaxf(mst, m);
            const float sf = exp2f(mst - mn);
            mst = mn;
            lst *= sf;
#pragma unroll
            for (int nd = 0; nd < 4; nd++) acc[nd] *= sf;
        }
        const float mm = mst;
        s16x4 pb[4];
        float pg[4];
#pragma unroll
        for (int nt = 0; nt < 4; nt++) {
            float p0 = exp2f(st[nt][0] - mm), p1 = exp2f(st[nt][1] - mm);
            float p2 = exp2f(st[nt][2] - mm), p3 = exp2f(st[nt][3] - mm);
            pg[nt] = (p0 + p1) + (p2 + p3);
            s16x4 pv;
            pv[0] = (short)__builtin_bit_cast(u16, (__bf16)p0);
            pv[1] = (short)__builtin_bit_cast(u16, (__bf16)p1);
            pv[2] = (short)__builtin_bit_cast(u16, (__bf16)p2);
            pv[3] = (short)__builtin_bit_cast(u16, (__bf16)p3);
            pb[nt] = pv;
        }
        float ps = (pg[0] + pg[1]) + (pg[2] + pg[3]);
        ps += __shfl_xor(ps, 16);
        ps += __shfl_xor(ps, 32);
        lst += ps;

        // --- O^T += V^T·P : paired A-frags, one b128 per (nt2,nd) ---
        const char* Vbase = (const char*)&Vtls[cur][0];
        __builtin_amdgcn_s_setprio(1);
#pragma unroll
        for (int nt2 = 0; nt2 < 2; nt2++) {
            const int rb = nt2 ? rb1 : rb0;
#pragma unroll
            for (int nd = 0; nd < 4; nd++) {
                ushort8 vvv = *(const ushort8*)(Vbase + nd * 2048 + rb);
                s16x4 vlo = { (short)vvv[0], (short)vvv[1], (short)vvv[2], (short)vvv[3] };
                s16x4 vhi = { (short)vvv[4], (short)vvv[5], (short)vvv[6], (short)vvv[7] };
                acc[nd] = __builtin_amdgcn_mfma_f32_16x16x16bf16_1k(
                    vlo, pb[2 * nt2], acc[nd], 0, 0, 0);
                acc[nd] = __builtin_amdgcn_mfma_f32_16x16x16bf16_1k(
                    vhi, pb[2 * nt2 + 1], acc[nd], 0, 0, 0);
            }
        }
        __builtin_amdgcn_s_setprio(0);

        // write next tile into the other buffer (no race with cur readers)
        if (kb + 1 < nkb) {
            const int nxt = cur ^ 1;
            *(ushort8*)((char*)&Kls[nxt][0] + klo0) = tk0;
            *(ushort8*)((char*)&Kls[nxt][0] + klo1) = tk1;
#pragma unroll
            for (int j = 0; j < 8; j++) {
                *((u16*)((char*)&Vtls[nxt][0] + (vd0*8+j) * 128 + (vpos2 ^ (j << 4)))) = tv0[j];
                *((u16*)((char*)&Vtls[nxt][0] + (vd1*8+j) * 128 + (vpos2 ^ (j << 4)))) = tv1[j];
            }
        }
        __syncthreads();
    }

    // --- epilogue: lane holds O^T[d=nd*16+l4*4+r][q=l15]; write /lst ---
    const int b = bh >> 4, h = bh & 15;
    const float inv = 1.0f / lst;
    const int q = qw + l15;
#pragma unroll
    for (int nd = 0; nd < 4; nd++) {
        u16x4 o;
#pragma unroll
        for (int r = 0; r < 4; r++)
            o[r] = __builtin_bit_cast(u16, (__bf16)(acc[nd][r] * inv));
        const int d = nd * 16 + l4 * 4;
        *(u16x4*)(Yb + (size_t)(b * SEQ + q) * D_MODEL + h * HDIM + d) = o;
    }
}

// ---------------------------------------------------------------------------
extern "C" void kernel_launch(void* const* d_in, const int* in_sizes, int n_in,
                              void* d_out, int out_size, void* d_ws, size_t ws_size,
                              hipStream_t stream)
{
    const float* x  = (const float*)d_in[0];
    const float* wq = (const float*)d_in[1];
    const float* wk = (const float*)d_in[2];
    const float* wv = (const float*)d_in[3];
    const float* wo = (const float*)d_in[4];
    const int*  pos = (const int*)d_in[5];
    float* out = (float*)d_out;

    // workspace layout (bf16 elements):
    // [x 4M | wq 1M | wk 1M | wv 1M | wo 1M | Q 4M | K 4M | V 4M] = 40 MiB
    // y (attention output) aliases x (x is dead after the QKV GEMM).
    if (ws_size < (size_t)41943040) return;
    u16* xb  = (u16*)d_ws;
    u16* wqb = xb  + (size_t)4 * SEG;
    u16* wkb = wqb + SEG;
    u16* wvb = wkb + SEG;
    u16* wob = wvb + SEG;
    u16* Qb  = wob + SEG;
    u16* Kb  = Qb  + (size_t)4 * SEG;
    u16* Vb  = Kb  + (size_t)4 * SEG;
    u16* Yb  = xb;

    k_cvt     <<<dim3(512, 1, 8), 256, 0, stream>>>(x, wq, wk, wv, wo, xb);
    k_gemm_qkv<<<dim3(8, 32, 3),  256, 0, stream>>>(xb, wqb, wkb, wvb, Qb, Kb, Vb);
    k_rope    <<<dim3(8192, 2),   256, 0, stream>>>(Qb, Kb, pos);
    k_attn    <<<dim3(32, 32),    256, 0, stream>>>(Qb, Kb, Vb, Yb);
    k_gemm_o  <<<dim3(8, 32),     256, 0, stream>>>(Yb, wob, out);
}